// Round 16
// baseline (157.762 us; speedup 1.0000x reference)
//
#include <hip/hip_runtime.h>
#include <hip/hip_bf16.h>

// Shapes: x:(16,32,128) mask:(16,128) w1:(256,66) b1:(256) w2:(128,256) b2:(128) pool_w:(128,21)
// L=128, L2=16384, dim=256, out_c=128. Output (16,128) f32.

#define NB 16
#define CIN 33
#define DIM 256
#define LEN 128
#define OC 128
#define L2 16384

typedef short bf16x8 __attribute__((ext_vector_type(8)));
typedef float f32x4 __attribute__((ext_vector_type(4)));

__device__ __forceinline__ unsigned short f32_to_bf16_rne(float f) {
    unsigned u = __float_as_uint(f);
    unsigned rb = ((u >> 16) & 1u) + 0x7FFFu;
    return (unsigned short)((u + rb) >> 16);
}
__device__ __forceinline__ float bf16_to_f32(unsigned short b) {
    return __uint_as_float(((unsigned)b) << 16);
}
// two f32 -> packed bf16 pair (v_cvt_pk_bf16_f32), RNE
__device__ __forceinline__ unsigned pk_bf16(float a, float b) {
    __hip_bfloat162 p = __float22bfloat162_rn(make_float2(a, b));
    unsigned w;
    __builtin_memcpy(&w, &p, 4);
    return w;
}

// ---------------- kernel A: ha/hb = w1a/w1b @ xm, with b1 folded in (half each) ----------------
__global__ __launch_bounds__(128) void kA(const float* __restrict__ x,
                                          const float* __restrict__ mask,
                                          const float* __restrict__ w1,
                                          const float* __restrict__ b1,
                                          float* __restrict__ ha,
                                          float* __restrict__ hb) {
    int d = blockIdx.x;
    int n = blockIdx.y;
    int l = threadIdx.x;
    const float* w1r = w1 + d * (2 * CIN);
    float a = 0.f, b = 0.f;
#pragma unroll
    for (int c = 0; c < CIN; ++c) {
        float xv = (c < 32) ? x[((size_t)n * 32 + c) * LEN + l] : mask[(size_t)n * LEN + l];
        a = fmaf(w1r[c], xv, a);
        b = fmaf(w1r[CIN + c], xv, b);
    }
    float hb1 = 0.5f * b1[d];
    ha[((size_t)n * DIM + d) * LEN + l] = a + hb1;
    hb[((size_t)n * DIM + d) * LEN + l] = b + hb1;
}

// ---------------- kernel W: split w2 into bf16 hi/lo ----------------
__global__ __launch_bounds__(256) void kW(const float* __restrict__ w2,
                                          unsigned short* __restrict__ w2hi,
                                          unsigned short* __restrict__ w2lo) {
    int idx = blockIdx.x * 256 + threadIdx.x;   // 32768 total
    float v = w2[idx];
    unsigned short h = f32_to_bf16_rne(v);
    unsigned short l = f32_to_bf16_rne(v - bf16_to_f32(h));
    w2hi[idx] = h;
    w2lo[idx] = l;
}

// ---------------- kernel B: MFMA GEMM, TWO i0 per block ----------------
// Per block (iPair, zloc): for i0 = 2*iPair and i0+1, C[o=128][j=128] = sum_d
// (w2hi+w2lo)[o,d] * bf16(relu(ha[d,i]+hb[d,j])) + b2[o].  hb and A-frags are shared
// between the two i values (hb is i-independent) -> global traffic per output halved.
#define ROWP 40
__global__ __launch_bounds__(256) void kB(const float* __restrict__ ha,
                                          const float* __restrict__ hb,
                                          const unsigned short* __restrict__ w2hi,
                                          const unsigned short* __restrict__ w2lo,
                                          const float* __restrict__ b2,
                                          unsigned short* __restrict__ y,
                                          int nbase) {
    __shared__ unsigned short Bh0[128 * ROWP], Bh1[128 * ROWP];
    __shared__ float ha_s[2 * DIM];
    int i0 = blockIdx.x * 2;
    int zloc = blockIdx.y;
    int n = nbase + zloc;
    int tid = threadIdx.x;
    int wv = tid >> 6, l = tid & 63;
    int g = l >> 4, lr = l & 15;

    if (tid < DIM) {
        const float* hp = ha + ((size_t)n * DIM + tid) * LEN + i0;
        ha_s[tid] = hp[0];
        ha_s[DIM + tid] = hp[1];
    }

    f32x4 acc0[2][8], acc1[2][8];
#pragma unroll
    for (int mt = 0; mt < 2; ++mt) {
        float bv[4];
#pragma unroll
        for (int r = 0; r < 4; ++r) bv[r] = b2[(wv * 2 + mt) * 16 + g * 4 + r];
#pragma unroll
        for (int nt = 0; nt < 8; ++nt)
#pragma unroll
            for (int r = 0; r < 4; ++r) {
                acc0[mt][nt][r] = bv[r];
                acc1[mt][nt][r] = bv[r];
            }
    }

    const float* hbN = hb + (size_t)n * DIM * LEN;
    int j = tid & 127, kh = tid >> 7;
    __syncthreads();

    for (int d0 = 0; d0 < DIM; d0 += 32) {
        // ---- build BOTH B tiles from shared hb loads ----
        {
            union { unsigned w[8]; uint4 q[2]; } p0, p1;
#pragma unroll
            for (int kk = 0; kk < 16; kk += 2) {
                int d = d0 + kh * 16 + kk;
                float hbv0 = hbN[(size_t)d * LEN + j];
                float hbv1 = hbN[(size_t)(d + 1) * LEN + j];
                p0.w[kk >> 1] = pk_bf16(fmaxf(ha_s[d] + hbv0, 0.f),
                                        fmaxf(ha_s[d + 1] + hbv1, 0.f));
                p1.w[kk >> 1] = pk_bf16(fmaxf(ha_s[DIM + d] + hbv0, 0.f),
                                        fmaxf(ha_s[DIM + d + 1] + hbv1, 0.f));
            }
            *(uint4*)&Bh0[j * ROWP + kh * 16] = p0.q[0];
            *(uint4*)&Bh0[j * ROWP + kh * 16 + 8] = p0.q[1];
            *(uint4*)&Bh1[j * ROWP + kh * 16] = p1.q[0];
            *(uint4*)&Bh1[j * ROWP + kh * 16 + 8] = p1.q[1];
        }
        __syncthreads();

        // ---- A frags straight from global (L2-hot; shared across both i) ----
        bf16x8 ah[2], al[2];
#pragma unroll
        for (int mt = 0; mt < 2; ++mt) {
            int row = (wv * 2 + mt) * 16 + lr;
            ah[mt] = *(const bf16x8*)&w2hi[(size_t)row * DIM + d0 + g * 8];
            al[mt] = *(const bf16x8*)&w2lo[(size_t)row * DIM + d0 + g * 8];
        }
#pragma unroll
        for (int nt = 0; nt < 8; ++nt) {
            int brow = nt * 16 + lr;
            bf16x8 bh0 = *(bf16x8*)&Bh0[brow * ROWP + g * 8];
            bf16x8 bh1 = *(bf16x8*)&Bh1[brow * ROWP + g * 8];
#pragma unroll
            for (int mt = 0; mt < 2; ++mt) {
                acc0[mt][nt] = __builtin_amdgcn_mfma_f32_16x16x32_bf16(ah[mt], bh0, acc0[mt][nt], 0, 0, 0);
                acc0[mt][nt] = __builtin_amdgcn_mfma_f32_16x16x32_bf16(al[mt], bh0, acc0[mt][nt], 0, 0, 0);
                acc1[mt][nt] = __builtin_amdgcn_mfma_f32_16x16x32_bf16(ah[mt], bh1, acc1[mt][nt], 0, 0, 0);
                acc1[mt][nt] = __builtin_amdgcn_mfma_f32_16x16x32_bf16(al[mt], bh1, acc1[mt][nt], 0, 0, 0);
            }
        }
        __syncthreads();
    }

#pragma unroll
    for (int mt = 0; mt < 2; ++mt)
#pragma unroll
        for (int nt = 0; nt < 8; ++nt)
#pragma unroll
            for (int r = 0; r < 4; ++r) {
                int o = (wv * 2 + mt) * 16 + g * 4 + r;
                int col = nt * 16 + lr;
                size_t base = ((size_t)zloc * OC + o) * L2 + (size_t)i0 * LEN + col;
                y[base] = f32_to_bf16_rne(acc0[mt][nt][r]);
                y[base + LEN] = f32_to_bf16_rne(acc1[mt][nt][r]);
            }
}

// ---------------- kernel C: rank-slot histogram pooling (swizzled, low-VGPR) ----------------
// Measured-best variant (88.6 us): single atomic pass with saved intra-bin offsets,
// start-writeback, plain-broadcast claim reads, per-element reference weight formula.
__device__ __forceinline__ unsigned swz(unsigned w) { return w ^ ((w >> 2) & 0xCu); }

__global__ __launch_bounds__(1024, 8) void kC(const unsigned short* __restrict__ y,
                                              const float* __restrict__ pw,
                                              float* __restrict__ out,
                                              int nbase) {
    extern __shared__ unsigned hist[];   // 16384 + 16 words
    int row = blockIdx.x;
    int och = row & (OC - 1);
    int n = nbase + (row >> 7);
    int t = threadIdx.x;
    int lane = t & 63, wv = t >> 6;
    const unsigned short* yr = y + (size_t)row * L2;
    const float* pwo = pw + och * 21;
    int tsw = (t & 3) << 2;              // quad swizzle offset for this thread's block

    // 1. zero own 16 words
#pragma unroll
    for (int q = 0; q < 4; ++q)
        *(uint4*)&hist[t * 16 + ((q << 2) ^ tsw)] = make_uint4(0, 0, 0, 0);
    __syncthreads();

    // 2. histogram; save intra-bin offsets from atomic returns (ld dies after this phase)
    unsigned off16[8];
    {
        union { uint4 q[2]; unsigned short u[16]; } ld;
        ld.q[0] = *(const uint4*)&yr[t * 16];
        ld.q[1] = *(const uint4*)&yr[t * 16 + 8];
#pragma unroll
        for (int e = 0; e < 16; ++e) {
            unsigned u = ld.u[e];
            unsigned k16 = u ^ ((u & 0x8000u) ? 0xFFFFu : 0x8000u);
            unsigned hi = (k16 >> 1) & 1;
            unsigned old = atomicAdd(&hist[swz(k16 >> 2)], hi ? 0x10000u : 1u);
            unsigned myoff = hi ? (old >> 16) : (old & 0xFFFFu);
            if (e & 1) off16[e >> 1] |= myoff << 16;
            else       off16[e >> 1] = myoff;
        }
    }
    __syncthreads();

    // 3a. own-bin total (re-read quads; no register cache)
    int Ti = 0;
#pragma unroll
    for (int q = 0; q < 4; ++q) {
        uint4 v4 = *(const uint4*)&hist[t * 16 + ((q << 2) ^ tsw)];
        Ti += (int)(v4.x & 0xFFFFu) + (int)(v4.x >> 16);
        Ti += (int)(v4.y & 0xFFFFu) + (int)(v4.y >> 16);
        Ti += (int)(v4.z & 0xFFFFu) + (int)(v4.z >> 16);
        Ti += (int)(v4.w & 0xFFFFu) + (int)(v4.w >> 16);
    }
    int incl = Ti;
#pragma unroll
    for (int d = 1; d < 64; d <<= 1) {
        int u2 = __shfl_up(incl, d, 64);
        if (lane >= d) incl += u2;
    }
    if (lane == 63) hist[16384 + wv] = (unsigned)incl;   // wave totals in dedicated scratch
    __syncthreads();
    int base = 0;
#pragma unroll
    for (int k = 0; k < 16; ++k) {
        int tw = (int)hist[16384 + k];                   // broadcast read
        base += (k < wv) ? tw : 0;
    }
    int P = base + (incl - Ti);          // ascending exclusive prefix before this thread's bins

    // 3b. re-read quads, write back per-bin descending-rank starts: start(b) = L2 - P_incl(b)
#pragma unroll
    for (int q = 0; q < 4; ++q) {
        unsigned* wp = &hist[t * 16 + ((q << 2) ^ tsw)];
        uint4 v4 = *(const uint4*)wp;
        unsigned r4[4] = {v4.x, v4.y, v4.z, v4.w};
#pragma unroll
        for (int c = 0; c < 4; ++c) {
            int clo = (int)(r4[c] & 0xFFFFu), chi = (int)(r4[c] >> 16);
            P += clo;
            unsigned slo = (unsigned)(L2 - P);
            P += chi;
            unsigned shi = (unsigned)(L2 - P);
            r4[c] = slo | (shi << 16);
        }
        *(uint4*)wp = make_uint4(r4[0], r4[1], r4[2], r4[3]);
    }
    __syncthreads();

    // 4. re-read y (L2-hot); rank = bin start + saved offset; apply reference weight formula
    float acc = 0.f;
    {
        union { uint4 q[2]; unsigned short u[16]; } ld;
        ld.q[0] = *(const uint4*)&yr[t * 16];
        ld.q[1] = *(const uint4*)&yr[t * 16 + 8];
#pragma unroll
        for (int e = 0; e < 16; ++e) {
            unsigned u = ld.u[e];
            unsigned k16 = u ^ ((u & 0x8000u) ? 0xFFFFu : 0x8000u);
            unsigned hi = (k16 >> 1) & 1;
            unsigned w = hist[swz(k16 >> 2)];            // same-word reads broadcast
            unsigned start = hi ? (w >> 16) : (w & 0xFFFFu);
            unsigned myoff = (e & 1) ? (off16[e >> 1] >> 16) : (off16[e >> 1] & 0xFFFFu);
            int r = (int)(start + myoff);
            float posf = fminf((float)r / 16383.0f, 1.0f);
            float idxf = 20.0f * posf;
            int idx = (int)idxf;
            float frac = idxf - (float)idx;
            int i1 = min(idx + 1, 20);
            float wvw = (1.0f - frac) * pwo[idx] + frac * pwo[i1];
            float val = __uint_as_float(((unsigned)u) << 16);
            acc = fmaf(val, wvw, acc);
        }
    }

    // 5. reduce (scratch words reused after barrier)
#pragma unroll
    for (int d = 32; d >= 1; d >>= 1) acc += __shfl_xor(acc, d, 64);
    __syncthreads();
    if (lane == 0) ((float*)hist)[16384 + wv] = acc;
    __syncthreads();
    if (t == 0) {
        double tot = 0.0;
#pragma unroll
        for (int k = 0; k < 16; ++k) tot += (double)((const float*)hist)[16384 + k];
        out[(size_t)n * OC + och] = (float)(tot * (1.0 / (double)L2));
    }
}

extern "C" void kernel_launch(void* const* d_in, const int* in_sizes, int n_in,
                              void* d_out, int out_size, void* d_ws, size_t ws_size,
                              hipStream_t stream) {
    const float* x    = (const float*)d_in[0];
    const float* mask = (const float*)d_in[1];
    const float* w1   = (const float*)d_in[2];
    const float* b1   = (const float*)d_in[3];
    const float* w2   = (const float*)d_in[4];
    const float* b2   = (const float*)d_in[5];
    const float* pw   = (const float*)d_in[6];
    float* out = (float*)d_out;

    char* ws = (char*)d_ws;
    float* ha = (float*)ws;                                       // 2 MB
    float* hb = ha + (size_t)NB * DIM * LEN;                      // 2 MB
    unsigned short* w2hi = (unsigned short*)(ws + (size_t)2 * NB * DIM * LEN * 4);  // 64 KB
    unsigned short* w2lo = w2hi + (size_t)OC * DIM;                                  // 64 KB
    unsigned short* y = w2lo + (size_t)OC * DIM;                  // up to 64 MB bf16

    size_t used = (size_t)2 * NB * DIM * LEN * 4 + (size_t)2 * OC * DIM * 2;
    size_t perN = (size_t)OC * L2 * 2;   // 4 MB per n (bf16)
    int nchunk = 1;
    if (ws_size > used + perN) {
        size_t c = (ws_size - used) / perN;
        nchunk = (int)(c > NB ? NB : c);
    }

    hipLaunchKernelGGL(kA, dim3(DIM, NB), dim3(128), 0, stream, x, mask, w1, b1, ha, hb);
    hipLaunchKernelGGL(kW, dim3(OC * DIM / 256), dim3(256), 0, stream, w2, w2hi, w2lo);
    for (int base = 0; base < NB; base += nchunk) {
        int nc = nchunk < (NB - base) ? nchunk : (NB - base);
        hipLaunchKernelGGL(kB, dim3(LEN / 2, nc), dim3(256), 0, stream, ha, hb, w2hi, w2lo, b2, y, base);
        hipLaunchKernelGGL(kC, dim3(OC * nc), dim3(1024), 65600, stream, y, pw, out, base);
    }
}

// Round 17
// 126.697 us; speedup vs baseline: 1.2452x; 1.2452x over previous
//
#include <hip/hip_runtime.h>
#include <hip/hip_bf16.h>

// Shapes: x:(16,32,128) mask:(16,128) w1:(256,66) b1:(256) w2:(128,256) b2:(128) pool_w:(128,21)
// L=128, L2=16384, dim=256, out_c=128. Output (16,128) f32.

#define NB 16
#define CIN 33
#define DIM 256
#define LEN 128
#define OC 128
#define L2 16384

typedef short bf16x8 __attribute__((ext_vector_type(8)));
typedef float f32x4 __attribute__((ext_vector_type(4)));

__device__ __forceinline__ unsigned short f32_to_bf16_rne(float f) {
    unsigned u = __float_as_uint(f);
    unsigned rb = ((u >> 16) & 1u) + 0x7FFFu;
    return (unsigned short)((u + rb) >> 16);
}
__device__ __forceinline__ float bf16_to_f32(unsigned short b) {
    return __uint_as_float(((unsigned)b) << 16);
}
// two f32 -> packed bf16 pair (v_cvt_pk_bf16_f32), RNE
__device__ __forceinline__ unsigned pk_bf16(float a, float b) {
    __hip_bfloat162 p = __float22bfloat162_rn(make_float2(a, b));
    unsigned w;
    __builtin_memcpy(&w, &p, 4);
    return w;
}

// ---------------- kernel A: ha/hb = w1a/w1b @ xm, with b1 folded in (half each) ----------------
__global__ __launch_bounds__(128) void kA(const float* __restrict__ x,
                                          const float* __restrict__ mask,
                                          const float* __restrict__ w1,
                                          const float* __restrict__ b1,
                                          float* __restrict__ ha,
                                          float* __restrict__ hb) {
    int d = blockIdx.x;
    int n = blockIdx.y;
    int l = threadIdx.x;
    const float* w1r = w1 + d * (2 * CIN);
    float a = 0.f, b = 0.f;
#pragma unroll
    for (int c = 0; c < CIN; ++c) {
        float xv = (c < 32) ? x[((size_t)n * 32 + c) * LEN + l] : mask[(size_t)n * LEN + l];
        a = fmaf(w1r[c], xv, a);
        b = fmaf(w1r[CIN + c], xv, b);
    }
    float hb1 = 0.5f * b1[d];
    ha[((size_t)n * DIM + d) * LEN + l] = a + hb1;
    hb[((size_t)n * DIM + d) * LEN + l] = b + hb1;
}

// ---------------- kernel W: w2 -> bf16 ----------------
__global__ __launch_bounds__(256) void kW(const float* __restrict__ w2,
                                          unsigned short* __restrict__ w2h) {
    int idx = blockIdx.x * 256 + threadIdx.x;   // 32768 total
    w2h[idx] = f32_to_bf16_rne(w2[idx]);
}

// ---------------- kernel B: MFMA GEMM, bf16 A (from global), bf16 B ----------------
// Per block (i0, zloc): C[o=128][j=128] = sum_d bf16(w2)[o,d] * bf16(relu(ha[d,i0]+hb[d,j])) + b2[o]
// 256 threads = 4 waves; wave wv owns M-tiles {2wv,2wv+1} x all 8 N-tiles. K-step 32.
// LDS: only the B tile (10 KB). A frags read straight from L2-hot w2h.
#define ROWP 40
__global__ __launch_bounds__(256) void kB(const float* __restrict__ ha,
                                          const float* __restrict__ hb,
                                          const unsigned short* __restrict__ w2h,
                                          const float* __restrict__ b2,
                                          unsigned short* __restrict__ y,
                                          int nbase) {
    __shared__ unsigned short Bh[128 * ROWP];
    __shared__ float ha_s[DIM];
    int i0 = blockIdx.x;
    int zloc = blockIdx.y;
    int n = nbase + zloc;
    int tid = threadIdx.x;
    int wv = tid >> 6, l = tid & 63;
    int g = l >> 4, lr = l & 15;

    if (tid < DIM) ha_s[tid] = ha[((size_t)n * DIM + tid) * LEN + i0];

    f32x4 acc[2][8];
#pragma unroll
    for (int mt = 0; mt < 2; ++mt) {
        float bv[4];
#pragma unroll
        for (int r = 0; r < 4; ++r) bv[r] = b2[(wv * 2 + mt) * 16 + g * 4 + r];
#pragma unroll
        for (int nt = 0; nt < 8; ++nt)
#pragma unroll
            for (int r = 0; r < 4; ++r) acc[mt][nt][r] = bv[r];
    }

    const float* hbN = hb + (size_t)n * DIM * LEN;
    int j = tid & 127, kh = tid >> 7;
    __syncthreads();

    for (int d0 = 0; d0 < DIM; d0 += 32) {
        // ---- build B tile: Bh[j][k] = bf16(relu(ha[d]+hb[d][j])), 16 k per thread ----
        {
            union { unsigned w[8]; uint4 q[2]; } pkv;
#pragma unroll
            for (int kk = 0; kk < 16; kk += 2) {
                int d = d0 + kh * 16 + kk;
                float h0 = fmaxf(ha_s[d] + hbN[(size_t)d * LEN + j], 0.f);
                float h1 = fmaxf(ha_s[d + 1] + hbN[(size_t)(d + 1) * LEN + j], 0.f);
                pkv.w[kk >> 1] = pk_bf16(h0, h1);
            }
            *(uint4*)&Bh[j * ROWP + kh * 16] = pkv.q[0];
            *(uint4*)&Bh[j * ROWP + kh * 16 + 8] = pkv.q[1];
        }
        __syncthreads();

        // ---- A frags straight from global (L2-hot; same for all blocks) ----
        bf16x8 ah[2];
#pragma unroll
        for (int mt = 0; mt < 2; ++mt) {
            int row = (wv * 2 + mt) * 16 + lr;
            ah[mt] = *(const bf16x8*)&w2h[(size_t)row * DIM + d0 + g * 8];
        }
#pragma unroll
        for (int nt = 0; nt < 8; ++nt) {
            int brow = nt * 16 + lr;
            bf16x8 bh = *(bf16x8*)&Bh[brow * ROWP + g * 8];
#pragma unroll
            for (int mt = 0; mt < 2; ++mt)
                acc[mt][nt] = __builtin_amdgcn_mfma_f32_16x16x32_bf16(ah[mt], bh, acc[mt][nt], 0, 0, 0);
        }
        __syncthreads();
    }

#pragma unroll
    for (int mt = 0; mt < 2; ++mt)
#pragma unroll
        for (int nt = 0; nt < 8; ++nt)
#pragma unroll
            for (int r = 0; r < 4; ++r) {
                int o = (wv * 2 + mt) * 16 + g * 4 + r;
                int col = nt * 16 + lr;
                y[((size_t)zloc * OC + o) * L2 + (size_t)i0 * LEN + col] =
                    f32_to_bf16_rne(acc[mt][nt][r]);
            }
}

// ---------------- kernel C: rank-slot histogram pooling (swizzled, low-VGPR) ----------------
// Measured-best variant (88.6 us) + pw staged in a padded LDS table (22 entries) so the
// per-element weight lookup is 2 near-broadcast LDS reads and no clamp on idx+1.
__device__ __forceinline__ unsigned swz(unsigned w) { return w ^ ((w >> 2) & 0xCu); }

__global__ __launch_bounds__(1024, 8) void kC(const unsigned short* __restrict__ y,
                                              const float* __restrict__ pw,
                                              float* __restrict__ out,
                                              int nbase) {
    extern __shared__ unsigned hist[];   // 16384 counts + 16 wave totals + 22 pwT
    int row = blockIdx.x;
    int och = row & (OC - 1);
    int n = nbase + (row >> 7);
    int t = threadIdx.x;
    int lane = t & 63, wv = t >> 6;
    const unsigned short* yr = y + (size_t)row * L2;
    const float* pwo = pw + och * 21;
    float* pwT = (float*)&hist[16384 + 16];
    int tsw = (t & 3) << 2;              // quad swizzle offset for this thread's block

    // 1. zero own 16 words + stage pw table (padded: pwT[21] = pwo[20])
#pragma unroll
    for (int q = 0; q < 4; ++q)
        *(uint4*)&hist[t * 16 + ((q << 2) ^ tsw)] = make_uint4(0, 0, 0, 0);
    if (t < 21) pwT[t] = pwo[t];
    if (t == 21) pwT[21] = pwo[20];
    __syncthreads();

    // 2. histogram; save intra-bin offsets from atomic returns
    unsigned off16[8];
    {
        union { uint4 q[2]; unsigned short u[16]; } ld;
        ld.q[0] = *(const uint4*)&yr[t * 16];
        ld.q[1] = *(const uint4*)&yr[t * 16 + 8];
#pragma unroll
        for (int e = 0; e < 16; ++e) {
            unsigned u = ld.u[e];
            unsigned k16 = u ^ ((u & 0x8000u) ? 0xFFFFu : 0x8000u);
            unsigned hi = (k16 >> 1) & 1;
            unsigned old = atomicAdd(&hist[swz(k16 >> 2)], hi ? 0x10000u : 1u);
            unsigned myoff = hi ? (old >> 16) : (old & 0xFFFFu);
            if (e & 1) off16[e >> 1] |= myoff << 16;
            else       off16[e >> 1] = myoff;
        }
    }
    __syncthreads();

    // 3a. own-bin total (re-read quads; no register cache)
    int Ti = 0;
#pragma unroll
    for (int q = 0; q < 4; ++q) {
        uint4 v4 = *(const uint4*)&hist[t * 16 + ((q << 2) ^ tsw)];
        Ti += (int)(v4.x & 0xFFFFu) + (int)(v4.x >> 16);
        Ti += (int)(v4.y & 0xFFFFu) + (int)(v4.y >> 16);
        Ti += (int)(v4.z & 0xFFFFu) + (int)(v4.z >> 16);
        Ti += (int)(v4.w & 0xFFFFu) + (int)(v4.w >> 16);
    }
    int incl = Ti;
#pragma unroll
    for (int d = 1; d < 64; d <<= 1) {
        int u2 = __shfl_up(incl, d, 64);
        if (lane >= d) incl += u2;
    }
    if (lane == 63) hist[16384 + wv] = (unsigned)incl;   // wave totals in dedicated scratch
    __syncthreads();
    int base = 0;
#pragma unroll
    for (int k = 0; k < 16; ++k) {
        int tw = (int)hist[16384 + k];                   // broadcast read
        base += (k < wv) ? tw : 0;
    }
    int P = base + (incl - Ti);          // ascending exclusive prefix before this thread's bins

    // 3b. re-read quads, write back per-bin descending-rank starts: start(b) = L2 - P_incl(b)
#pragma unroll
    for (int q = 0; q < 4; ++q) {
        unsigned* wp = &hist[t * 16 + ((q << 2) ^ tsw)];
        uint4 v4 = *(const uint4*)wp;
        unsigned r4[4] = {v4.x, v4.y, v4.z, v4.w};
#pragma unroll
        for (int c = 0; c < 4; ++c) {
            int clo = (int)(r4[c] & 0xFFFFu), chi = (int)(r4[c] >> 16);
            P += clo;
            unsigned slo = (unsigned)(L2 - P);
            P += chi;
            unsigned shi = (unsigned)(L2 - P);
            r4[c] = slo | (shi << 16);
        }
        *(uint4*)wp = make_uint4(r4[0], r4[1], r4[2], r4[3]);
    }
    __syncthreads();

    // 4. re-read y (L2-hot); rank = bin start + saved offset; weight via LDS pw table
    float acc = 0.f;
    {
        union { uint4 q[2]; unsigned short u[16]; } ld;
        ld.q[0] = *(const uint4*)&yr[t * 16];
        ld.q[1] = *(const uint4*)&yr[t * 16 + 8];
#pragma unroll
        for (int e = 0; e < 16; ++e) {
            unsigned u = ld.u[e];
            unsigned k16 = u ^ ((u & 0x8000u) ? 0xFFFFu : 0x8000u);
            unsigned hi = (k16 >> 1) & 1;
            unsigned w = hist[swz(k16 >> 2)];            // same-word reads broadcast
            unsigned start = hi ? (w >> 16) : (w & 0xFFFFu);
            unsigned myoff = (e & 1) ? (off16[e >> 1] >> 16) : (off16[e >> 1] & 0xFFFFu);
            int r = (int)(start + myoff);
            float posf = fminf((float)r * (1.0f / 16383.0f), 1.0f);
            float idxf = 20.0f * posf;
            int idx = (int)idxf;
            float frac = idxf - (float)idx;
            float wvw = (1.0f - frac) * pwT[idx] + frac * pwT[idx + 1];
            float val = __uint_as_float(((unsigned)u) << 16);
            acc = fmaf(val, wvw, acc);
        }
    }

    // 5. reduce (scratch words reused after barrier)
#pragma unroll
    for (int d = 32; d >= 1; d >>= 1) acc += __shfl_xor(acc, d, 64);
    __syncthreads();
    if (lane == 0) ((float*)hist)[16384 + wv] = acc;
    __syncthreads();
    if (t == 0) {
        double tot = 0.0;
#pragma unroll
        for (int k = 0; k < 16; ++k) tot += (double)((const float*)hist)[16384 + k];
        out[(size_t)n * OC + och] = (float)(tot * (1.0 / (double)L2));
    }
}

extern "C" void kernel_launch(void* const* d_in, const int* in_sizes, int n_in,
                              void* d_out, int out_size, void* d_ws, size_t ws_size,
                              hipStream_t stream) {
    const float* x    = (const float*)d_in[0];
    const float* mask = (const float*)d_in[1];
    const float* w1   = (const float*)d_in[2];
    const float* b1   = (const float*)d_in[3];
    const float* w2   = (const float*)d_in[4];
    const float* b2   = (const float*)d_in[5];
    const float* pw   = (const float*)d_in[6];
    float* out = (float*)d_out;

    char* ws = (char*)d_ws;
    float* ha = (float*)ws;                                       // 2 MB
    float* hb = ha + (size_t)NB * DIM * LEN;                      // 2 MB
    unsigned short* w2h = (unsigned short*)(ws + (size_t)2 * NB * DIM * LEN * 4);   // 64 KB
    unsigned short* y = w2h + (size_t)2 * OC * DIM;               // up to 64 MB bf16

    size_t used = (size_t)2 * NB * DIM * LEN * 4 + (size_t)2 * OC * DIM * 2;
    size_t perN = (size_t)OC * L2 * 2;   // 4 MB per n (bf16)
    int nchunk = 1;
    if (ws_size > used + perN) {
        size_t c = (ws_size - used) / perN;
        nchunk = (int)(c > NB ? NB : c);
    }

    hipLaunchKernelGGL(kA, dim3(DIM, NB), dim3(128), 0, stream, x, mask, w1, b1, ha, hb);
    hipLaunchKernelGGL(kW, dim3(OC * DIM / 256), dim3(256), 0, stream, w2, w2h);
    for (int base = 0; base < NB; base += nchunk) {
        int nc = nchunk < (NB - base) ? nchunk : (NB - base);
        hipLaunchKernelGGL(kB, dim3(LEN, nc), dim3(256), 0, stream, ha, hb, w2h, b2, y, base);
        hipLaunchKernelGGL(kC, dim3(OC * nc), dim3(1024), (16384 + 16 + 22) * 4, stream, y, pw, out, base);
    }
}